// Round 7
// baseline (4141.093 us; speedup 1.0000x reference)
//
#include <hip/hip_runtime.h>
#include <hip/hip_bf16.h>
#include <stdint.h>

// Bidirectional 2-layer LSTM decoder: B=16, T=512, E=H=1024.
// Round-7: stop broadcasting through the MALL.
//  - h0 (write-once history): producer sc1 stores + drain + sc1 flag; consumers
//    poll the flag (sc1) then PLAIN-load the data -> L2-shared across the 32
//    blocks of each XCD (64KB/XCD/step from MALL instead of 12MB chip-wide).
//    Safe: each h0 address is first touched only after its flag; values are
//    launch-deterministic so cross-launch stale lines are benign.
//  - h1 (ring, addresses reused): SENTINEL protocol. 0xFFFF bf16 (-NaN) is
//    never produced by tanh. Producer stores data sc1 fire-and-forget (no
//    drain, no flag). Consumers poll-load the data until no sentinel dword.
//    Ring R=4: at step t read slot (t+3)&3, write t&3, reset (t+1)&3 (holds
//    h1(t-3): provably unread once any block reaches step t). Resets drain
//    via the wave's own later poll vmcnt(0), before that slot's next write.
//  - Weights stay pinned in VGPRs (l0, l1-h0) and LDS (l1-h1).

#define TT 512
#define HH 1024

typedef __bf16 bf16x8 __attribute__((ext_vector_type(8)));
typedef float f32x4 __attribute__((ext_vector_type(4)));
typedef unsigned int u32;
typedef unsigned short u16;

#define MFMA __builtin_amdgcn_mfma_f32_16x16x32_bf16

// ---- workspace layout (bytes) ----
#define OFS_FLAGS 0ul            // [2][64] u32 l0 flags (zeroed each launch)
#define OFS_B0    4096ul         // [2][4096] f32
#define OFS_B1    36864ul        // [2][4096] f32
#define OFS_X     69632ul        // [8192][1024] bf16
#define OFS_WIH0  16846848ul     // packed [2][64][4][32][64][8] bf16
#define OFS_WHH0  33624064ul     // same shape
#define OFS_W1    50401280ul     // packed [2][64][4][96][64][8] bf16 (h0 64ks | h1 32ks)
#define OFS_H0    100732928ul    // [512][2][16][1024] bf16 (write-once history)
#define OFS_H1    134287360ul    // [4][2][16][1024] bf16 ring (sentinel protocol)
// end ~134.55 MB

__device__ inline u16 f2b(float f){
  union { float f; u32 u; } x{f};
  return (u16)((x.u + 0x7FFFu + ((x.u >> 16) & 1u)) >> 16);
}
__device__ inline float sigm(float x){ return 1.f/(1.f + __expf(-x)); }
__device__ inline float tanh_(float x){ return 2.f*sigm(2.f*x) - 1.f; }

// ---- coherent (MALL-level) helpers: plain vmcnt semantics ----
__device__ inline u32 g_poll1(const u32* p){
  u32 v;
  asm volatile("global_load_dword %0, %1, off sc0 sc1\n\t"
               "s_waitcnt vmcnt(0)" : "=&v"(v) : "v"(p) : "memory");
  return v;
}
__device__ inline void g_poll2(const u32* p, const u32* q, u32& a, u32& b){
  asm volatile("global_load_dword %0, %2, off sc0 sc1\n\t"
               "global_load_dword %1, %3, off sc0 sc1\n\t"
               "s_waitcnt vmcnt(0)"
               : "=&v"(a), "=&v"(b) : "v"(p), "v"(q) : "memory");
}
__device__ inline void g_store32(u32* p, u32 v){
  asm volatile("global_store_dword %0, %1, off sc0 sc1" :: "v"(p), "v"(v) : "memory");
}

// 8x16B coherent load batch (h1 sentinel poll), one waitcnt per batch
#define G_LOAD8(A, P) asm volatile( \
  "global_load_dwordx4 %0, %8, off sc0 sc1\n\t" \
  "global_load_dwordx4 %1, %8, off offset:64 sc0 sc1\n\t" \
  "global_load_dwordx4 %2, %8, off offset:128 sc0 sc1\n\t" \
  "global_load_dwordx4 %3, %8, off offset:192 sc0 sc1\n\t" \
  "global_load_dwordx4 %4, %8, off offset:256 sc0 sc1\n\t" \
  "global_load_dwordx4 %5, %8, off offset:320 sc0 sc1\n\t" \
  "global_load_dwordx4 %6, %8, off offset:384 sc0 sc1\n\t" \
  "global_load_dwordx4 %7, %8, off offset:448 sc0 sc1\n\t" \
  "s_waitcnt vmcnt(0)" \
  : "=&v"(A[0]), "=&v"(A[1]), "=&v"(A[2]), "=&v"(A[3]), \
    "=&v"(A[4]), "=&v"(A[5]), "=&v"(A[6]), "=&v"(A[7]) \
  : "v"(P) : "memory")

__device__ inline int frag_ok(const f32x4 v){
  uint4 u = __builtin_bit_cast(uint4, v);
  return (u.x != 0xFFFFFFFFu) & (u.y != 0xFFFFFFFFu) &
         (u.z != 0xFFFFFFFFu) & (u.w != 0xFFFFFFFFu);
}

__global__ void k_bias(const float* __restrict__ a0, const float* __restrict__ a1,
                       const float* __restrict__ a2, const float* __restrict__ a3,
                       float* __restrict__ b0, float* __restrict__ b1){
  int i = blockIdx.x*256 + threadIdx.x;
  if (i < 8192){ b0[i] = a0[i] + a1[i]; b1[i] = a2[i] + a3[i]; }
}

__global__ void k_embed(const int* __restrict__ inputs, const float* __restrict__ emb,
                        u16* __restrict__ X){
  int row = blockIdx.x;                 // t*16 + b
  int t = row >> 4, b = row & 15;
  int tok = (t == 0) ? 1 : inputs[b*TT + t];   // BOS=1 at t=0
  const float4* src = (const float4*)(emb + (size_t)tok*HH);
  float4 v = src[threadIdx.x];
  ushort4 o = make_ushort4(f2b(v.x), f2b(v.y), f2b(v.z), f2b(v.w));
  ((ushort4*)X)[(size_t)row*256 + threadIdx.x] = o;
}

// pack W[n][k] fp32 -> fragment-major bf16, frag elem j <-> k = ks*32+(l>>4)*8+j
__global__ void k_pack(const float* __restrict__ sA, const float* __restrict__ sB,
                       int KA, int KB, u16* __restrict__ dst){
  int K = KA + KB, KS = K >> 5;
  long idx = (long)blockIdx.x*256 + threadIdx.x;
  long total = 2L*64*4*KS*64;
  if (idx >= total) return;
  int l = (int)(idx & 63);
  long r = idx >> 6;
  int ks = (int)(r % KS); r /= KS;
  int g  = (int)(r & 3);  r >>= 2;
  int jb = (int)(r & 63); r >>= 6;
  int cell = (int)r;
  int n  = g*1024 + jb*16 + (l & 15);
  int k0 = ks*32 + ((l >> 4) << 3);
  const float* s; int kl;
  if (k0 < KA){ s = sA + (long)(cell*4096 + n)*KA; kl = k0; }
  else        { s = sB + (long)(cell*4096 + n)*KB; kl = k0 - KA; }
  float4 f0 = *(const float4*)(s + kl);
  float4 f1 = *(const float4*)(s + kl + 4);
  union { u16 v[8]; int4 q; } o;
  o.v[0]=f2b(f0.x); o.v[1]=f2b(f0.y); o.v[2]=f2b(f0.z); o.v[3]=f2b(f0.w);
  o.v[4]=f2b(f1.x); o.v[5]=f2b(f1.y); o.v[6]=f2b(f1.z); o.v[7]=f2b(f1.w);
  long d = ((((long)cell*64 + jb)*4 + g)*KS + ks)*64 + l;
  ((int4*)dst)[d] = o.q;
}

__global__ __launch_bounds__(256, 1)
void k_fused(const u16* __restrict__ Wih0p, const u16* __restrict__ Whh0p,
             const u16* __restrict__ W1p, const float* __restrict__ b0,
             const float* __restrict__ b1, const u16* __restrict__ Xb,
             u16* h0_all, u16* h1r, float* __restrict__ out, u32* flags)
{
  extern __shared__ char smem[];
  float*  gl   = (float*)smem;                  // [4 waves][4 gates][256] partials
  f32x4*  wlds = (f32x4*)(smem + 16384);        // l1 h1-weights [4][32][64] frags

  const int tid  = threadIdx.x;
  const int wv   = tid >> 6, l = tid & 63;
  const int rowA = l & 15;
  const int kq8  = (l >> 4) * 8;
  const int layer = blockIdx.x >> 7;
  const int bid   = blockIdx.x & 127;
  const int cell  = bid >> 6, jb = bid & 63;
  const int b_ = tid >> 4, j = tid & 15;

  float bias[4];
  {
    const float* bb = (layer == 0 ? b0 : b1) + cell*4096 + jb*16 + rowA;
    #pragma unroll
    for (int g = 0; g < 4; g++) bias[g] = (wv == 0) ? bb[g*1024] : 0.f;
  }
  float creg = 0.f;

  if (layer == 0){
    // wave 0,1: ih (X); wave 2,3: hh (h0). ks slice (wv&1)*16..+15
    f32x4 w[4][16];
    {
      const f32x4* src = (const f32x4*)(wv < 2 ? Wih0p : Whh0p)
                       + ((long)(cell*64 + jb)*4)*32*64 + l;
      #pragma unroll
      for (int g = 0; g < 4; g++)
        #pragma unroll
        for (int i = 0; i < 16; i++)
          w[g][i] = src[((long)g*32 + ((wv & 1)*16 + i))*64];
    }
    #pragma unroll
    for (int g = 0; g < 4; g++)
      #pragma unroll
      for (int i = 0; i < 16; i++) asm volatile("" : "+v"(w[g][i]));
    __syncthreads();

    const u32* flr = flags + cell*64;
    u32* myf = flags + cell*64 + jb;
    u32* hdst = (u32*)h0_all;
    const int ko = (wv & 1) * 512;

    for (int t = 0; t < TT; t++){
      f32x4 acc[4];
      #pragma unroll
      for (int g = 0; g < 4; g++) acc[g] = (f32x4){bias[g],bias[g],bias[g],bias[g]};
      if (wv < 2){
        // ih part: no dependency, runs while wave3 polls
        const u16* A = Xb + ((long)t*16 + rowA)*1024 + ko + kq8;
        f32x4 Af[16];
        #pragma unroll
        for (int i = 0; i < 16; i++) Af[i] = *(const f32x4*)(A + i*32);
        #pragma unroll
        for (int i = 0; i < 16; i++)
          #pragma unroll
          for (int g = 0; g < 4; g++)
            acc[g] = MFMA(__builtin_bit_cast(bf16x8, Af[i]),
                          __builtin_bit_cast(bf16x8, w[g][i]), acc[g], 0, 0, 0);
        int r0 = (l >> 4)*4, cj = l & 15;
        #pragma unroll
        for (int g = 0; g < 4; g++)
          #pragma unroll
          for (int i2 = 0; i2 < 4; i2++)
            gl[wv*1024 + g*256 + (r0+i2)*16 + cj] = acc[g][i2];
      } else if (wv == 3 && t > 0){
        while (!__all((int)(g_poll1(flr + l) >= (u32)t))) {}
      }
      __syncthreads();                          // A: h0(t-1) flagged ready
      if (wv >= 2){
        if (t > 0){
          // PLAIN loads: L2-shared within the XCD (fresh: first touch post-flag)
          const u16* A = h0_all + (((long)(t-1)*2 + cell)*16 + rowA)*1024 + ko + kq8;
          f32x4 Af[16];
          #pragma unroll
          for (int i = 0; i < 16; i++) Af[i] = *(const f32x4*)(A + i*32);
          #pragma unroll
          for (int i = 0; i < 16; i++)
            #pragma unroll
            for (int g = 0; g < 4; g++)
              acc[g] = MFMA(__builtin_bit_cast(bf16x8, Af[i]),
                            __builtin_bit_cast(bf16x8, w[g][i]), acc[g], 0, 0, 0);
        }
        int r0 = (l >> 4)*4, cj = l & 15;
        #pragma unroll
        for (int g = 0; g < 4; g++)
          #pragma unroll
          for (int i2 = 0; i2 < 4; i2++)
            gl[wv*1024 + g*256 + (r0+i2)*16 + cj] = acc[g][i2];
      }
      __syncthreads();                          // B: all partials in gl
      {
        float gi = gl[tid]      + gl[1024+tid] + gl[2048+tid] + gl[3072+tid];
        float gf = gl[256+tid]  + gl[1280+tid] + gl[2304+tid] + gl[3328+tid];
        float gg = gl[512+tid]  + gl[1536+tid] + gl[2560+tid] + gl[3584+tid];
        float go = gl[768+tid]  + gl[1792+tid] + gl[2816+tid] + gl[3840+tid];
        float c2 = sigm(gf)*creg + sigm(gi)*tanh_(gg);
        float h2 = sigm(go)*tanh_(c2);
        creg = c2;
        u32 lo = f2b(h2), hi = __shfl_down(lo, 1);
        if (!(tid & 1)){
          long idx = ((((long)t*2 + cell)*16 + b_)*1024 + jb*16 + j) >> 1;
          g_store32(hdst + idx, lo | (hi << 16));
        }
        asm volatile("s_waitcnt vmcnt(0)" ::: "memory");  // drain before flag
      }
      __syncthreads();                          // C: all stores at MALL
      if (tid == 0) g_store32(myf, (u32)(t+1));
    }
  } else {
    // l1: h0-part (weights in VGPR), h1-part ks wv*8..+7 (weights in LDS)
    f32x4 w[4][16];
    {
      const f32x4* src = (const f32x4*)W1p + ((long)(cell*64 + jb)*4)*96*64 + l;
      #pragma unroll
      for (int g = 0; g < 4; g++)
        #pragma unroll
        for (int i = 0; i < 16; i++)
          w[g][i] = src[((long)g*96 + wv*16 + i)*64];
      const f32x4* wb = (const f32x4*)W1p + (long)((cell*64 + jb)*4)*96*64;
      for (int i = tid; i < 8192; i += 256){
        int g = i >> 11, ks = (i >> 6) & 31, ll = i & 63;
        wlds[i] = wb[((long)g*96 + 64 + ks)*64 + ll];
      }
    }
    #pragma unroll
    for (int g = 0; g < 4; g++)
      #pragma unroll
      for (int i = 0; i < 16; i++) asm volatile("" : "+v"(w[g][i]));
    __syncthreads();

    const u32* fl0 = flags;
    const u32* fl1 = flags + 64;
    const f32x4* wl = wlds + (wv*8)*64 + l;
    u32* h1d = (u32*)h1r;

    for (int t = 0; t < TT; t++){
      // reset slot (t+1)&3 (holds h1(t-3); unread once any block is at t).
      // Drained by this wave's h1 sentinel poll below, before next-step write.
      {
        int rs = (t + 1) & 3;
        if (!(tid & 1)){
          long idx = ((((long)rs*2 + cell)*16 + b_)*1024 + jb*16 + j) >> 1;
          g_store32(h1d + idx, 0xFFFFFFFFu);
        }
      }
      if (wv == 3){
        const u32 tgt = (u32)(t + 1);
        for (;;){
          u32 a, b; g_poll2(fl0 + l, fl1 + l, a, b);
          if (__all((int)(a >= tgt && b >= tgt))) break;
        }
      }
      __syncthreads();                          // A: h0f(t), h0b(t) ready
      f32x4 acc[4];
      #pragma unroll
      for (int g = 0; g < 4; g++) acc[g] = (f32x4){bias[g],bias[g],bias[g],bias[g]};
      {
        // PLAIN loads (L2-shared)
        const u16* A = h0_all + (((long)t*2 + (wv >> 1))*16 + rowA)*1024
                     + (wv & 1)*512 + kq8;
        f32x4 Af[16];
        #pragma unroll
        for (int i = 0; i < 16; i++) Af[i] = *(const f32x4*)(A + i*32);
        #pragma unroll
        for (int i = 0; i < 16; i++)
          #pragma unroll
          for (int g = 0; g < 4; g++)
            acc[g] = MFMA(__builtin_bit_cast(bf16x8, Af[i]),
                          __builtin_bit_cast(bf16x8, w[g][i]), acc[g], 0, 0, 0);
      }
      {
        // h1(t-1) sentinel poll: the load IS the sync (no flag, no drain)
        int tm = (t + 3) & 3;
        const u16* Ah = h1r + (((long)tm*2 + cell)*16 + rowA)*1024 + wv*256 + kq8;
        f32x4 Bf[8];
        for (;;){
          G_LOAD8(Bf, Ah);
          int ok = 1;
          #pragma unroll
          for (int i = 0; i < 8; i++) ok &= frag_ok(Bf[i]);
          if (__all(ok)) break;
        }
        #pragma unroll
        for (int i = 0; i < 8; i++)
          #pragma unroll
          for (int g = 0; g < 4; g++)
            acc[g] = MFMA(__builtin_bit_cast(bf16x8, Bf[i]),
                          __builtin_bit_cast(bf16x8, wl[(g*32 + i)*64]),
                          acc[g], 0, 0, 0);
      }
      {
        int r0 = (l >> 4)*4, cj = l & 15;
        #pragma unroll
        for (int g = 0; g < 4; g++)
          #pragma unroll
          for (int i2 = 0; i2 < 4; i2++)
            gl[wv*1024 + g*256 + (r0+i2)*16 + cj] = acc[g][i2];
      }
      __syncthreads();                          // C: partials in gl
      {
        float gi = gl[tid]      + gl[1024+tid] + gl[2048+tid] + gl[3072+tid];
        float gf = gl[256+tid]  + gl[1280+tid] + gl[2304+tid] + gl[3328+tid];
        float gg = gl[512+tid]  + gl[1536+tid] + gl[2560+tid] + gl[3584+tid];
        float go = gl[768+tid]  + gl[1792+tid] + gl[2816+tid] + gl[3840+tid];
        float c2 = sigm(gf)*creg + sigm(gi)*tanh_(gg);
        float h2 = sigm(go)*tanh_(c2);
        creg = c2;
        out[((long)b_*TT + t)*2048 + cell*1024 + jb*16 + j] = h2;
        u32 lo = f2b(h2), hi = __shfl_down(lo, 1);
        if (!(tid & 1)){
          long idx = ((((long)(t & 3)*2 + cell)*16 + b_)*1024 + jb*16 + j) >> 1;
          g_store32(h1d + idx, lo | (hi << 16));   // fire-and-forget
        }
      }
      __syncthreads();                          // D: gl safe to reuse
    }
  }
}

extern "C" void kernel_launch(void* const* d_in, const int* in_sizes, int n_in,
                              void* d_out, int out_size, void* d_ws, size_t ws_size,
                              hipStream_t stream){
  const int*   inputs = (const int*)d_in[0];
  const float* emb    = (const float*)d_in[1];
  const float* wih0   = (const float*)d_in[2];
  const float* whh0   = (const float*)d_in[3];
  const float* bih0   = (const float*)d_in[4];
  const float* bhh0   = (const float*)d_in[5];
  const float* wih1   = (const float*)d_in[6];
  const float* whh1   = (const float*)d_in[7];
  const float* bih1   = (const float*)d_in[8];
  const float* bhh1   = (const float*)d_in[9];
  float* out = (float*)d_out;
  char* ws = (char*)d_ws;

  u32*   flags = (u32*)(ws + OFS_FLAGS);
  float* b0    = (float*)(ws + OFS_B0);
  float* b1    = (float*)(ws + OFS_B1);
  u16*   Xb    = (u16*)(ws + OFS_X);
  u16*   Wih0p = (u16*)(ws + OFS_WIH0);
  u16*   Whh0p = (u16*)(ws + OFS_WHH0);
  u16*   W1p   = (u16*)(ws + OFS_W1);
  u16*   h0a   = (u16*)(ws + OFS_H0);
  u16*   h1r   = (u16*)(ws + OFS_H1);

  hipMemsetAsync(flags, 0, 4096, stream);
  // h1 ring: slots 0-2 sentinel (0xFFFF), slot 3 zeros (h1(-1)=0, read at t=0)
  hipMemsetAsync(ws + OFS_H1, 0xFF, 196608, stream);
  hipMemsetAsync(ws + OFS_H1 + 196608, 0x00, 65536, stream);
  k_bias <<<32,   256, 0, stream>>>(bih0, bhh0, bih1, bhh1, b0, b1);
  k_embed<<<8192, 256, 0, stream>>>(inputs, emb, Xb);
  k_pack <<<4096, 256, 0, stream>>>(wih0, (const float*)0, 1024, 0, Wih0p);
  k_pack <<<4096, 256, 0, stream>>>(whh0, (const float*)0, 1024, 0, Whh0p);
  k_pack <<<12288,256, 0, stream>>>(wih1, whh1, 2048, 1024, W1p);

  const int smem_bytes = 16384 + 131072;
  hipFuncSetAttribute(reinterpret_cast<const void*>(&k_fused),
                      hipFuncAttributeMaxDynamicSharedMemorySize, smem_bytes);
  k_fused<<<256, 256, smem_bytes, stream>>>(Wih0p, Whh0p, W1p, b0, b1, Xb,
                                            h0a, h1r, out, flags);
}

// Round 8
// 3733.639 us; speedup vs baseline: 1.1091x; 1.1091x over previous
//
#include <hip/hip_runtime.h>
#include <hip/hip_bf16.h>
#include <stdint.h>

// Bidirectional 2-layer LSTM decoder: B=16, T=512, E=H=1024.
// Round-8: guarantee weight residency + tighten sync.
//  - 512 threads / 8 waves per block, launch_bounds(512,2) (VGPR cap 256).
//    Per-wave weights: l0 = 32 frags (128 VGPR); l1 = 32 h0-frags (128) +
//    4 h1-frags (16) + 24 h1-ks in LDS (96KB). Round 4-7 had 256+ weight
//    VGPRs per wave vs VGPR_Count=196 -> weights were NOT resident.
//  - l0: waves 0-3 ih (X, plain loads), waves 4-7 hh (h0, plain loads);
//    wave 7 polls the cell's 64 flags. One poll, 3 barriers per step.
//  - l1: wave 7 polls fl0+fl1, wave 6 polls flo IN PARALLEL, one barrier.
//    h1 sc1 loads issue-early / vmcnt(0)-late so the MALL RT hides under
//    the h0-part MFMAs.
//  - h0 write-once history + plain consumer loads (first touch post-flag;
//    values launch-deterministic so stale-identical lines are benign).
//  - h1 ring(4) + flag flo; producer sc1 stores + drain + flag (sound).

#define TT 512
#define HH 1024

typedef __bf16 bf16x8 __attribute__((ext_vector_type(8)));
typedef float f32x4 __attribute__((ext_vector_type(4)));
typedef unsigned int u32;
typedef unsigned short u16;

#define MFMA __builtin_amdgcn_mfma_f32_16x16x32_bf16

// ---- workspace layout (bytes) ----
#define OFS_FLAGS 0ul            // [4][64] u32 flags (zeroed each launch)
#define OFS_B0    4096ul         // [2][4096] f32
#define OFS_B1    36864ul        // [2][4096] f32
#define OFS_X     69632ul        // [8192][1024] bf16
#define OFS_WIH0  16846848ul     // packed [2][64][4][32][64][8] bf16
#define OFS_WHH0  33624064ul     // same shape
#define OFS_W1    50401280ul     // packed [2][64][4][96][64][8] bf16 (h0 64ks | h1 32ks)
#define OFS_H0    100732928ul    // [512][2][16][1024] bf16 (write-once history)
#define OFS_H1    134287360ul    // [4][2][16][1024] bf16 ring
// end ~134.55 MB

__device__ inline u16 f2b(float f){
  union { float f; u32 u; } x{f};
  return (u16)((x.u + 0x7FFFu + ((x.u >> 16) & 1u)) >> 16);
}
__device__ inline float sigm(float x){ return 1.f/(1.f + __expf(-x)); }
__device__ inline float tanh_(float x){ return 2.f*sigm(2.f*x) - 1.f; }

// ---- coherent (MALL-level) helpers ----
__device__ inline u32 g_poll1(const u32* p){
  u32 v;
  asm volatile("global_load_dword %0, %1, off sc0 sc1\n\t"
               "s_waitcnt vmcnt(0)" : "=&v"(v) : "v"(p) : "memory");
  return v;
}
__device__ inline void g_poll2(const u32* p, const u32* q, u32& a, u32& b){
  asm volatile("global_load_dword %0, %2, off sc0 sc1\n\t"
               "global_load_dword %1, %3, off sc0 sc1\n\t"
               "s_waitcnt vmcnt(0)"
               : "=&v"(a), "=&v"(b) : "v"(p), "v"(q) : "memory");
}
__device__ inline void g_store32(u32* p, u32 v){
  asm volatile("global_store_dword %0, %1, off sc0 sc1" :: "v"(p), "v"(v) : "memory");
}

// issue 4x16B sc1 loads WITHOUT waiting (wait later with G_WAIT0)
#define G_LOAD4_ISSUE(A, P) asm volatile( \
  "global_load_dwordx4 %0, %4, off sc0 sc1\n\t" \
  "global_load_dwordx4 %1, %4, off offset:64 sc0 sc1\n\t" \
  "global_load_dwordx4 %2, %4, off offset:128 sc0 sc1\n\t" \
  "global_load_dwordx4 %3, %4, off offset:192 sc0 sc1" \
  : "=&v"(A[0]), "=&v"(A[1]), "=&v"(A[2]), "=&v"(A[3]) \
  : "v"(P) : "memory")
#define G_WAIT0() asm volatile("s_waitcnt vmcnt(0)" ::: "memory")

__global__ void k_bias(const float* __restrict__ a0, const float* __restrict__ a1,
                       const float* __restrict__ a2, const float* __restrict__ a3,
                       float* __restrict__ b0, float* __restrict__ b1,
                       unsigned long long* __restrict__ h1z){
  int i = blockIdx.x*256 + threadIdx.x;
  if (i < 8192){ b0[i] = a0[i] + a1[i]; b1[i] = a2[i] + a3[i]; h1z[i] = 0ull; }
}

__global__ void k_embed(const int* __restrict__ inputs, const float* __restrict__ emb,
                        u16* __restrict__ X){
  int row = blockIdx.x;                 // t*16 + b
  int t = row >> 4, b = row & 15;
  int tok = (t == 0) ? 1 : inputs[b*TT + t];   // BOS=1 at t=0
  const float4* src = (const float4*)(emb + (size_t)tok*HH);
  float4 v = src[threadIdx.x];
  ushort4 o = make_ushort4(f2b(v.x), f2b(v.y), f2b(v.z), f2b(v.w));
  ((ushort4*)X)[(size_t)row*256 + threadIdx.x] = o;
}

// pack W[n][k] fp32 -> fragment-major bf16, frag elem j <-> k = ks*32+(l>>4)*8+j
__global__ void k_pack(const float* __restrict__ sA, const float* __restrict__ sB,
                       int KA, int KB, u16* __restrict__ dst){
  int K = KA + KB, KS = K >> 5;
  long idx = (long)blockIdx.x*256 + threadIdx.x;
  long total = 2L*64*4*KS*64;
  if (idx >= total) return;
  int l = (int)(idx & 63);
  long r = idx >> 6;
  int ks = (int)(r % KS); r /= KS;
  int g  = (int)(r & 3);  r >>= 2;
  int jb = (int)(r & 63); r >>= 6;
  int cell = (int)r;
  int n  = g*1024 + jb*16 + (l & 15);
  int k0 = ks*32 + ((l >> 4) << 3);
  const float* s; int kl;
  if (k0 < KA){ s = sA + (long)(cell*4096 + n)*KA; kl = k0; }
  else        { s = sB + (long)(cell*4096 + n)*KB; kl = k0 - KA; }
  float4 f0 = *(const float4*)(s + kl);
  float4 f1 = *(const float4*)(s + kl + 4);
  union { u16 v[8]; int4 q; } o;
  o.v[0]=f2b(f0.x); o.v[1]=f2b(f0.y); o.v[2]=f2b(f0.z); o.v[3]=f2b(f0.w);
  o.v[4]=f2b(f1.x); o.v[5]=f2b(f1.y); o.v[6]=f2b(f1.z); o.v[7]=f2b(f1.w);
  long d = ((((long)cell*64 + jb)*4 + g)*KS + ks)*64 + l;
  ((int4*)dst)[d] = o.q;
}

__global__ __launch_bounds__(512, 2)
void k_fused(const u16* __restrict__ Wih0p, const u16* __restrict__ Whh0p,
             const u16* __restrict__ W1p, const float* __restrict__ b0,
             const float* __restrict__ b1, const u16* __restrict__ Xb,
             u16* h0_all, u16* h1r, float* __restrict__ out, u32* flags)
{
  extern __shared__ char smem[];
  float*  gl   = (float*)smem;                  // [8 waves][4 gates][256] partials
  f32x4*  wlds = (f32x4*)(smem + 32768);        // l1 h1-weights [4][24][64] frags

  const int tid  = threadIdx.x;
  const int wv   = tid >> 6, l = tid & 63;
  const int rowA = l & 15;
  const int kq8  = (l >> 4) * 8;
  const int layer = blockIdx.x >> 7;
  const int bid   = blockIdx.x & 127;
  const int cell  = bid >> 6, jb = bid & 63;
  const int b_ = tid >> 4, j = tid & 15;        // epilogue ownership (tid<256)

  float bias[4];
  {
    const float* bb = (layer == 0 ? b0 : b1) + cell*4096 + jb*16 + rowA;
    #pragma unroll
    for (int g = 0; g < 4; g++) bias[g] = (wv == 0) ? bb[g*1024] : 0.f;
  }
  float creg = 0.f;

  if (layer == 0){
    // waves 0-3: ih (X) ks (wv&3)*8..+7 ; waves 4-7: hh (h0) ks (wv&3)*8..+7
    f32x4 w[4][8];
    {
      const f32x4* src = (const f32x4*)(wv < 4 ? Wih0p : Whh0p)
                       + ((long)(cell*64 + jb)*4)*32*64 + l;
      #pragma unroll
      for (int g = 0; g < 4; g++)
        #pragma unroll
        for (int i = 0; i < 8; i++)
          w[g][i] = src[((long)g*32 + (wv & 3)*8 + i)*64];
    }
    #pragma unroll
    for (int g = 0; g < 4; g++)
      #pragma unroll
      for (int i = 0; i < 8; i++) asm volatile("" : "+v"(w[g][i]));
    __syncthreads();

    const u32* flr = flags + cell*64;
    u32* myf = flags + cell*64 + jb;
    u32* hdst = (u32*)h0_all;
    const int ko = (wv & 3)*256;

    for (int t = 0; t < TT; t++){
      f32x4 acc[4];
      #pragma unroll
      for (int g = 0; g < 4; g++) acc[g] = (f32x4){bias[g],bias[g],bias[g],bias[g]};
      if (wv < 4){
        // ih: independent, runs while wave 7 polls
        const u16* A = Xb + ((long)t*16 + rowA)*1024 + ko + kq8;
        f32x4 Af[8];
        #pragma unroll
        for (int i = 0; i < 8; i++) Af[i] = *(const f32x4*)(A + i*32);
        #pragma unroll
        for (int i = 0; i < 8; i++)
          #pragma unroll
          for (int g = 0; g < 4; g++)
            acc[g] = MFMA(__builtin_bit_cast(bf16x8, Af[i]),
                          __builtin_bit_cast(bf16x8, w[g][i]), acc[g], 0, 0, 0);
        int r0 = (l >> 4)*4, cj = l & 15;
        #pragma unroll
        for (int g = 0; g < 4; g++)
          #pragma unroll
          for (int i2 = 0; i2 < 4; i2++)
            gl[wv*1024 + g*256 + (r0+i2)*16 + cj] = acc[g][i2];
      } else if (wv == 7 && t > 0){
        while (!__all((int)(g_poll1(flr + l) >= (u32)t))) {}
      }
      __syncthreads();                          // A: h0(t-1) flagged ready
      if (wv >= 4){
        if (t > 0){
          const u16* A = h0_all + (((long)(t-1)*2 + cell)*16 + rowA)*1024 + ko + kq8;
          f32x4 Af[8];
          #pragma unroll
          for (int i = 0; i < 8; i++) Af[i] = *(const f32x4*)(A + i*32);
          #pragma unroll
          for (int i = 0; i < 8; i++)
            #pragma unroll
            for (int g = 0; g < 4; g++)
              acc[g] = MFMA(__builtin_bit_cast(bf16x8, Af[i]),
                            __builtin_bit_cast(bf16x8, w[g][i]), acc[g], 0, 0, 0);
        }
        int r0 = (l >> 4)*4, cj = l & 15;
        #pragma unroll
        for (int g = 0; g < 4; g++)
          #pragma unroll
          for (int i2 = 0; i2 < 4; i2++)
            gl[wv*1024 + g*256 + (r0+i2)*16 + cj] = acc[g][i2];
      }
      __syncthreads();                          // B: all 8 partials in gl
      if (tid < 256){
        float s0=0.f, s1=0.f, s2=0.f, s3=0.f;
        #pragma unroll
        for (int wq = 0; wq < 8; wq++){
          s0 += gl[wq*1024 + tid];
          s1 += gl[wq*1024 + 256 + tid];
          s2 += gl[wq*1024 + 512 + tid];
          s3 += gl[wq*1024 + 768 + tid];
        }
        float c2 = sigm(s1)*creg + sigm(s0)*tanh_(s2);
        float h2 = sigm(s3)*tanh_(c2);
        creg = c2;
        u32 lo = f2b(h2), hi = __shfl_down(lo, 1);
        if (!(tid & 1)){
          long idx = ((((long)t*2 + cell)*16 + b_)*1024 + jb*16 + j) >> 1;
          g_store32(hdst + idx, lo | (hi << 16));
        }
        G_WAIT0();                              // drain h stores before flag
      }
      __syncthreads();                          // C: stores at MALL
      if (tid == 0) g_store32(myf, (u32)(t+1));
    }
  } else {
    // l1: per wave: h0 ks wv*8..+7 (VGPR), h1 ks 64+wv*4 (VGPR) + 3 in LDS
    f32x4 wh0[4][8];
    f32x4 wh1[4];
    {
      const f32x4* src = (const f32x4*)W1p + ((long)(cell*64 + jb)*4)*96*64 + l;
      #pragma unroll
      for (int g = 0; g < 4; g++){
        #pragma unroll
        for (int i = 0; i < 8; i++)
          wh0[g][i] = src[((long)g*96 + wv*8 + i)*64];
        wh1[g] = src[((long)g*96 + 64 + wv*4)*64];
      }
      const f32x4* wb = (const f32x4*)W1p + ((long)(cell*64 + jb)*4)*96*64;
      for (int i = tid; i < 6144; i += 512){
        int g = i / 1536, r = (i % 1536) >> 6, ll = i & 63;
        int ksl = 64 + (r/3)*4 + (r%3) + 1;
        wlds[i] = wb[((long)g*96 + ksl)*64 + ll];
      }
    }
    #pragma unroll
    for (int g = 0; g < 4; g++){
      #pragma unroll
      for (int i = 0; i < 8; i++) asm volatile("" : "+v"(wh0[g][i]));
      asm volatile("" : "+v"(wh1[g]));
    }
    __syncthreads();

    const u32* fl0 = flags;
    const u32* fl1 = flags + 64;
    const u32* flo = flags + (2 + cell)*64;
    u32* myf = flags + (2 + cell)*64 + jb;
    u32* h1d = (u32*)h1r;

    for (int t = 0; t < TT; t++){
      if (wv == 7){
        const u32 tgt = (u32)(t + 1);
        for (;;){
          u32 a, b; g_poll2(fl0 + l, fl1 + l, a, b);
          if (__all((int)(a >= tgt && b >= tgt))) break;
        }
      } else if (wv == 6 && t > 0){
        while (!__all((int)(g_poll1(flo + l) >= (u32)t))) {}
      }
      __syncthreads();                          // A: h0(t) and h1(t-1) ready
      f32x4 acc[4];
      #pragma unroll
      for (int g = 0; g < 4; g++) acc[g] = (f32x4){bias[g],bias[g],bias[g],bias[g]};
      // h1 loads issue early (MALL RT hides under h0-part compute)
      f32x4 Bf[4];
      {
        const u16* Ah = h1r + (((long)((t+3)&3)*2 + cell)*16 + rowA)*1024
                      + wv*128 + kq8;
        G_LOAD4_ISSUE(Bf, Ah);
      }
      {
        const u16* A = h0_all + ((long)t*32 + (wv>>2)*16 + rowA)*1024
                     + (wv & 3)*256 + kq8;
        f32x4 Af[8];
        #pragma unroll
        for (int i = 0; i < 8; i++) Af[i] = *(const f32x4*)(A + i*32);
        #pragma unroll
        for (int i = 0; i < 8; i++)
          #pragma unroll
          for (int g = 0; g < 4; g++)
            acc[g] = MFMA(__builtin_bit_cast(bf16x8, Af[i]),
                          __builtin_bit_cast(bf16x8, wh0[g][i]), acc[g], 0, 0, 0);
      }
      G_WAIT0();                                // h1 data arrived
      #pragma unroll
      for (int i = 0; i < 4; i++)
        #pragma unroll
        for (int g = 0; g < 4; g++){
          f32x4 bw = (i == 0) ? wh1[g] : wlds[(g*24 + wv*3 + (i-1))*64 + l];
          acc[g] = MFMA(__builtin_bit_cast(bf16x8, Bf[i]),
                        __builtin_bit_cast(bf16x8, bw), acc[g], 0, 0, 0);
        }
      {
        int r0 = (l >> 4)*4, cj = l & 15;
        #pragma unroll
        for (int g = 0; g < 4; g++)
          #pragma unroll
          for (int i2 = 0; i2 < 4; i2++)
            gl[wv*1024 + g*256 + (r0+i2)*16 + cj] = acc[g][i2];
      }
      __syncthreads();                          // B: partials in gl
      if (tid < 256){
        float s0=0.f, s1=0.f, s2=0.f, s3=0.f;
        #pragma unroll
        for (int wq = 0; wq < 8; wq++){
          s0 += gl[wq*1024 + tid];
          s1 += gl[wq*1024 + 256 + tid];
          s2 += gl[wq*1024 + 512 + tid];
          s3 += gl[wq*1024 + 768 + tid];
        }
        float c2 = sigm(s1)*creg + sigm(s0)*tanh_(s2);
        float h2 = sigm(s3)*tanh_(c2);
        creg = c2;
        out[((long)b_*TT + t)*2048 + cell*1024 + jb*16 + j] = h2;
        u32 lo = f2b(h2), hi = __shfl_down(lo, 1);
        if (!(tid & 1)){
          long idx = ((((long)(t & 3)*2 + cell)*16 + b_)*1024 + jb*16 + j) >> 1;
          g_store32(h1d + idx, lo | (hi << 16));
        }
        G_WAIT0();                              // drain h1 stores before flag
      }
      __syncthreads();                          // C
      if (tid == 0) g_store32(myf, (u32)(t+1));
    }
  }
}

extern "C" void kernel_launch(void* const* d_in, const int* in_sizes, int n_in,
                              void* d_out, int out_size, void* d_ws, size_t ws_size,
                              hipStream_t stream){
  const int*   inputs = (const int*)d_in[0];
  const float* emb    = (const float*)d_in[1];
  const float* wih0   = (const float*)d_in[2];
  const float* whh0   = (const float*)d_in[3];
  const float* bih0   = (const float*)d_in[4];
  const float* bhh0   = (const float*)d_in[5];
  const float* wih1   = (const float*)d_in[6];
  const float* whh1   = (const float*)d_in[7];
  const float* bih1   = (const float*)d_in[8];
  const float* bhh1   = (const float*)d_in[9];
  float* out = (float*)d_out;
  char* ws = (char*)d_ws;

  u32*   flags = (u32*)(ws + OFS_FLAGS);
  float* b0    = (float*)(ws + OFS_B0);
  float* b1    = (float*)(ws + OFS_B1);
  u16*   Xb    = (u16*)(ws + OFS_X);
  u16*   Wih0p = (u16*)(ws + OFS_WIH0);
  u16*   Whh0p = (u16*)(ws + OFS_WHH0);
  u16*   W1p   = (u16*)(ws + OFS_W1);
  u16*   h0a   = (u16*)(ws + OFS_H0);
  u16*   h1r   = (u16*)(ws + OFS_H1);
  unsigned long long* h1z = (unsigned long long*)(ws + OFS_H1 + 196608ul);

  hipMemsetAsync(flags, 0, 4096, stream);
  k_bias <<<32,   256, 0, stream>>>(bih0, bhh0, bih1, bhh1, b0, b1, h1z);
  k_embed<<<8192, 256, 0, stream>>>(inputs, emb, Xb);
  k_pack <<<4096, 256, 0, stream>>>(wih0, (const float*)0, 1024, 0, Wih0p);
  k_pack <<<4096, 256, 0, stream>>>(whh0, (const float*)0, 1024, 0, Whh0p);
  k_pack <<<12288,256, 0, stream>>>(wih1, whh1, 2048, 1024, W1p);

  const int smem_bytes = 32768 + 98304;   // gl 32KB + l1 h1-weight frags 96KB
  hipFuncSetAttribute(reinterpret_cast<const void*>(&k_fused),
                      hipFuncAttributeMaxDynamicSharedMemorySize, smem_bytes);
  k_fused<<<256, 512, smem_bytes, stream>>>(Wih0p, Whh0p, W1p, b0, b1, Xb,
                                            h0a, h1r, out, flags);
}

// Round 9
// 3043.056 us; speedup vs baseline: 1.3608x; 1.2269x over previous
//
#include <hip/hip_runtime.h>
#include <hip/hip_bf16.h>
#include <stdint.h>

// Bidirectional 2-layer LSTM decoder: B=16, T=512, E=H=1024.
// Round-9: data-is-the-flag (sentinel) everywhere -> minimum serial MALL RTs.
//  - h0 history is write-once: pre-filled 0xFF (bf16 -NaN sentinel, unreachable
//    from sigm*tanh). Producers store sc1 fire-and-forget: NO drain, NO flag.
//    Consumer waves poll their OWN A-fragments (sc1 dwordx4 batches) until no
//    dword is sentinel. Dword stores are atomic -> sentinel-or-data only.
//  - h1 ring(4), sentinel protocol (as R7): at step t read slot (t+3)&3, write
//    t&3, reset (t+1)&3 (holds h1(t-3), provably unread since poll success of
//    h1(t-1) implies all peer blocks >= t-1 epilogue). Reset/data stores are
//    drained by this wave's own later poll vmcnt(0)s before slot reuse.
//  - No flags, no store-drains, no poll waves; barriers 3 -> 2 per step.
//  - Weight layout as R8 (l0: 32 frags/wave; l1: 32 h0-frags + 4 h1-frags in
//    VGPR/AGPR + 24 h1-ks in LDS). 512 thr / 8 waves, launch_bounds(512,2).

#define TT 512
#define HH 1024

typedef __bf16 bf16x8 __attribute__((ext_vector_type(8)));
typedef float f32x4 __attribute__((ext_vector_type(4)));
typedef unsigned int u32;
typedef unsigned short u16;

#define MFMA __builtin_amdgcn_mfma_f32_16x16x32_bf16

// ---- workspace layout (bytes) ----
#define OFS_B0    4096ul         // [2][4096] f32
#define OFS_B1    36864ul        // [2][4096] f32
#define OFS_X     69632ul        // [8192][1024] bf16
#define OFS_WIH0  16846848ul     // packed [2][64][4][32][64][8] bf16
#define OFS_WHH0  33624064ul     // same shape
#define OFS_W1    50401280ul     // packed [2][64][4][96][64][8] bf16 (h0 64ks | h1 32ks)
#define OFS_H0    100732928ul    // [512][2][16][1024] bf16 (write-once, sentinel-armed)
#define OFS_H1    134287360ul    // [4][2][16][1024] bf16 ring (sentinel protocol)
// end ~134.55 MB

__device__ inline u16 f2b(float f){
  union { float f; u32 u; } x{f};
  return (u16)((x.u + 0x7FFFu + ((x.u >> 16) & 1u)) >> 16);
}
__device__ inline float sigm(float x){ return 1.f/(1.f + __expf(-x)); }
__device__ inline float tanh_(float x){ return 2.f*sigm(2.f*x) - 1.f; }

__device__ inline void g_store32(u32* p, u32 v){
  asm volatile("global_store_dword %0, %1, off sc0 sc1" :: "v"(p), "v"(v) : "memory");
}

// 8x16B coherent loads + single wait (sentinel poll body)
#define G_LOAD8(A, P) asm volatile( \
  "global_load_dwordx4 %0, %8, off sc0 sc1\n\t" \
  "global_load_dwordx4 %1, %8, off offset:64 sc0 sc1\n\t" \
  "global_load_dwordx4 %2, %8, off offset:128 sc0 sc1\n\t" \
  "global_load_dwordx4 %3, %8, off offset:192 sc0 sc1\n\t" \
  "global_load_dwordx4 %4, %8, off offset:256 sc0 sc1\n\t" \
  "global_load_dwordx4 %5, %8, off offset:320 sc0 sc1\n\t" \
  "global_load_dwordx4 %6, %8, off offset:384 sc0 sc1\n\t" \
  "global_load_dwordx4 %7, %8, off offset:448 sc0 sc1\n\t" \
  "s_waitcnt vmcnt(0)" \
  : "=&v"(A[0]), "=&v"(A[1]), "=&v"(A[2]), "=&v"(A[3]), \
    "=&v"(A[4]), "=&v"(A[5]), "=&v"(A[6]), "=&v"(A[7]) \
  : "v"(P) : "memory")

// issue 4x16B sc1 loads WITHOUT waiting
#define G_LOAD4_ISSUE(A, P) asm volatile( \
  "global_load_dwordx4 %0, %4, off sc0 sc1\n\t" \
  "global_load_dwordx4 %1, %4, off offset:64 sc0 sc1\n\t" \
  "global_load_dwordx4 %2, %4, off offset:128 sc0 sc1\n\t" \
  "global_load_dwordx4 %3, %4, off offset:192 sc0 sc1" \
  : "=&v"(A[0]), "=&v"(A[1]), "=&v"(A[2]), "=&v"(A[3]) \
  : "v"(P) : "memory")
// wait tied to the 4 result regs (orders later C++ uses after the wait)
#define G_WAIT4(A) asm volatile("s_waitcnt vmcnt(0)" \
  : "+v"(A[0]), "+v"(A[1]), "+v"(A[2]), "+v"(A[3]) :: "memory")
// reload 4 + wait (retry)
#define G_LOAD4W(A, P) asm volatile( \
  "global_load_dwordx4 %0, %4, off sc0 sc1\n\t" \
  "global_load_dwordx4 %1, %4, off offset:64 sc0 sc1\n\t" \
  "global_load_dwordx4 %2, %4, off offset:128 sc0 sc1\n\t" \
  "global_load_dwordx4 %3, %4, off offset:192 sc0 sc1\n\t" \
  "s_waitcnt vmcnt(0)" \
  : "=&v"(A[0]), "=&v"(A[1]), "=&v"(A[2]), "=&v"(A[3]) \
  : "v"(P) : "memory")

__device__ inline int frag_ok(const f32x4 v){
  uint4 u = __builtin_bit_cast(uint4, v);
  return (u.x != 0xFFFFFFFFu) & (u.y != 0xFFFFFFFFu) &
         (u.z != 0xFFFFFFFFu) & (u.w != 0xFFFFFFFFu);
}

__global__ void k_bias(const float* __restrict__ a0, const float* __restrict__ a1,
                       const float* __restrict__ a2, const float* __restrict__ a3,
                       float* __restrict__ b0, float* __restrict__ b1,
                       unsigned long long* __restrict__ h1z){
  int i = blockIdx.x*256 + threadIdx.x;
  if (i < 8192){ b0[i] = a0[i] + a1[i]; b1[i] = a2[i] + a3[i]; h1z[i] = 0ull; }
}

__global__ void k_embed(const int* __restrict__ inputs, const float* __restrict__ emb,
                        u16* __restrict__ X){
  int row = blockIdx.x;                 // t*16 + b
  int t = row >> 4, b = row & 15;
  int tok = (t == 0) ? 1 : inputs[b*TT + t];   // BOS=1 at t=0
  const float4* src = (const float4*)(emb + (size_t)tok*HH);
  float4 v = src[threadIdx.x];
  ushort4 o = make_ushort4(f2b(v.x), f2b(v.y), f2b(v.z), f2b(v.w));
  ((ushort4*)X)[(size_t)row*256 + threadIdx.x] = o;
}

// pack W[n][k] fp32 -> fragment-major bf16, frag elem j <-> k = ks*32+(l>>4)*8+j
__global__ void k_pack(const float* __restrict__ sA, const float* __restrict__ sB,
                       int KA, int KB, u16* __restrict__ dst){
  int K = KA + KB, KS = K >> 5;
  long idx = (long)blockIdx.x*256 + threadIdx.x;
  long total = 2L*64*4*KS*64;
  if (idx >= total) return;
  int l = (int)(idx & 63);
  long r = idx >> 6;
  int ks = (int)(r % KS); r /= KS;
  int g  = (int)(r & 3);  r >>= 2;
  int jb = (int)(r & 63); r >>= 6;
  int cell = (int)r;
  int n  = g*1024 + jb*16 + (l & 15);
  int k0 = ks*32 + ((l >> 4) << 3);
  const float* s; int kl;
  if (k0 < KA){ s = sA + (long)(cell*4096 + n)*KA; kl = k0; }
  else        { s = sB + (long)(cell*4096 + n)*KB; kl = k0 - KA; }
  float4 f0 = *(const float4*)(s + kl);
  float4 f1 = *(const float4*)(s + kl + 4);
  union { u16 v[8]; int4 q; } o;
  o.v[0]=f2b(f0.x); o.v[1]=f2b(f0.y); o.v[2]=f2b(f0.z); o.v[3]=f2b(f0.w);
  o.v[4]=f2b(f1.x); o.v[5]=f2b(f1.y); o.v[6]=f2b(f1.z); o.v[7]=f2b(f1.w);
  long d = ((((long)cell*64 + jb)*4 + g)*KS + ks)*64 + l;
  ((int4*)dst)[d] = o.q;
}

__global__ __launch_bounds__(512, 2)
void k_fused(const u16* __restrict__ Wih0p, const u16* __restrict__ Whh0p,
             const u16* __restrict__ W1p, const float* __restrict__ b0,
             const float* __restrict__ b1, const u16* __restrict__ Xb,
             u16* h0_all, u16* h1r, float* __restrict__ out)
{
  extern __shared__ char smem[];
  float*  gl   = (float*)smem;                  // [8 waves][4 gates][256] partials
  f32x4*  wlds = (f32x4*)(smem + 32768);        // l1 h1-weights [4][24][64] frags

  const int tid  = threadIdx.x;
  const int wv   = tid >> 6, l = tid & 63;
  const int rowA = l & 15;
  const int kq8  = (l >> 4) * 8;
  const int layer = blockIdx.x >> 7;
  const int bid   = blockIdx.x & 127;
  const int cell  = bid >> 6, jb = bid & 63;
  const int b_ = tid >> 4, j = tid & 15;        // epilogue ownership (tid<256)

  float bias[4];
  {
    const float* bb = (layer == 0 ? b0 : b1) + cell*4096 + jb*16 + rowA;
    #pragma unroll
    for (int g = 0; g < 4; g++) bias[g] = (wv == 0) ? bb[g*1024] : 0.f;
  }
  float creg = 0.f;

  if (layer == 0){
    // waves 0-3: ih (X) ks (wv&3)*8..+7 ; waves 4-7: hh (h0) ks (wv&3)*8..+7
    f32x4 w[4][8];
    {
      const f32x4* src = (const f32x4*)(wv < 4 ? Wih0p : Whh0p)
                       + ((long)(cell*64 + jb)*4)*32*64 + l;
      #pragma unroll
      for (int g = 0; g < 4; g++)
        #pragma unroll
        for (int i = 0; i < 8; i++)
          w[g][i] = src[((long)g*32 + (wv & 3)*8 + i)*64];
    }
    #pragma unroll
    for (int g = 0; g < 4; g++)
      #pragma unroll
      for (int i = 0; i < 8; i++) asm volatile("" : "+v"(w[g][i]));
    __syncthreads();

    u32* hdst = (u32*)h0_all;
    const int ko = (wv & 3)*256;

    for (int t = 0; t < TT; t++){
      f32x4 acc[4];
      #pragma unroll
      for (int g = 0; g < 4; g++) acc[g] = (f32x4){bias[g],bias[g],bias[g],bias[g]};
      if (wv < 4){
        const u16* A = Xb + ((long)t*16 + rowA)*1024 + ko + kq8;
        f32x4 Af[8];
        #pragma unroll
        for (int i = 0; i < 8; i++) Af[i] = *(const f32x4*)(A + i*32);
        #pragma unroll
        for (int i = 0; i < 8; i++)
          #pragma unroll
          for (int g = 0; g < 4; g++)
            acc[g] = MFMA(__builtin_bit_cast(bf16x8, Af[i]),
                          __builtin_bit_cast(bf16x8, w[g][i]), acc[g], 0, 0, 0);
      } else if (t > 0){
        // sentinel poll on own h0(t-1) fragments: the load IS the sync
        const u16* A = h0_all + (((long)(t-1)*2 + cell)*16 + rowA)*1024 + ko + kq8;
        f32x4 Af[8];
        for (;;){
          G_LOAD8(Af, A);
          int ok = 1;
          #pragma unroll
          for (int i = 0; i < 8; i++) ok &= frag_ok(Af[i]);
          if (__all(ok)) break;
        }
        #pragma unroll
        for (int i = 0; i < 8; i++)
          #pragma unroll
          for (int g = 0; g < 4; g++)
            acc[g] = MFMA(__builtin_bit_cast(bf16x8, Af[i]),
                          __builtin_bit_cast(bf16x8, w[g][i]), acc[g], 0, 0, 0);
      }
      {
        int r0 = (l >> 4)*4, cj = l & 15;
        #pragma unroll
        for (int g = 0; g < 4; g++)
          #pragma unroll
          for (int i2 = 0; i2 < 4; i2++)
            gl[wv*1024 + g*256 + (r0+i2)*16 + cj] = acc[g][i2];
      }
      __syncthreads();                          // B: all 8 partials in gl
      if (tid < 256){
        float s0=0.f, s1=0.f, s2=0.f, s3=0.f;
        #pragma unroll
        for (int wq = 0; wq < 8; wq++){
          s0 += gl[wq*1024 + tid];
          s1 += gl[wq*1024 + 256 + tid];
          s2 += gl[wq*1024 + 512 + tid];
          s3 += gl[wq*1024 + 768 + tid];
        }
        float c2 = sigm(s1)*creg + sigm(s0)*tanh_(s2);
        float h2 = sigm(s3)*tanh_(c2);
        creg = c2;
        u32 lo = f2b(h2), hi = __shfl_down(lo, 1);
        if (!(tid & 1)){
          long idx = ((((long)t*2 + cell)*16 + b_)*1024 + jb*16 + j) >> 1;
          g_store32(hdst + idx, lo | (hi << 16));   // fire-and-forget
        }
      }
      __syncthreads();                          // C: gl safe to reuse
    }
  } else {
    // l1: per wave: h0 ks wv*8..+7 (regs), h1 ks 64+wv*4 (1 frag reg + 3 LDS)
    f32x4 wh0[4][8];
    f32x4 wh1[4];
    {
      const f32x4* src = (const f32x4*)W1p + ((long)(cell*64 + jb)*4)*96*64 + l;
      #pragma unroll
      for (int g = 0; g < 4; g++){
        #pragma unroll
        for (int i = 0; i < 8; i++)
          wh0[g][i] = src[((long)g*96 + wv*8 + i)*64];
        wh1[g] = src[((long)g*96 + 64 + wv*4)*64];
      }
      const f32x4* wb = (const f32x4*)W1p + ((long)(cell*64 + jb)*4)*96*64;
      for (int i = tid; i < 6144; i += 512){
        int g = i / 1536, r = (i % 1536) >> 6, ll = i & 63;
        int ksl = 64 + (r/3)*4 + (r%3) + 1;
        wlds[i] = wb[((long)g*96 + ksl)*64 + ll];
      }
    }
    #pragma unroll
    for (int g = 0; g < 4; g++){
      #pragma unroll
      for (int i = 0; i < 8; i++) asm volatile("" : "+v"(wh0[g][i]));
      asm volatile("" : "+v"(wh1[g]));
    }
    __syncthreads();

    u32* h1d = (u32*)h1r;

    for (int t = 0; t < TT; t++){
      // reset slot (t+1)&3 (holds h1(t-3); all peers >= t-1 body => unread).
      // Drained by this wave's own poll vmcnt(0)s well before slot reuse.
      if (tid < 256 && !(tid & 1)){
        long idx = ((((long)((t+1)&3)*2 + cell)*16 + b_)*1024 + jb*16 + j) >> 1;
        g_store32(h1d + idx, 0xFFFFFFFFu);
      }
      // early-issue h1(t-1) attempt (hides under h0-part compute)
      f32x4 Bf[4];
      const u16* Ah = h1r + (((long)((t+3)&3)*2 + cell)*16 + rowA)*1024
                    + wv*128 + kq8;
      G_LOAD4_ISSUE(Bf, Ah);
      // h0f/h0b(t) sentinel poll on own fragments
      f32x4 acc[4];
      #pragma unroll
      for (int g = 0; g < 4; g++) acc[g] = (f32x4){bias[g],bias[g],bias[g],bias[g]};
      {
        const u16* A = h0_all + ((long)t*32 + (wv>>2)*16 + rowA)*1024
                     + (wv & 3)*256 + kq8;
        f32x4 Af[8];
        for (;;){
          G_LOAD8(Af, A);
          int ok = 1;
          #pragma unroll
          for (int i = 0; i < 8; i++) ok &= frag_ok(Af[i]);
          if (__all(ok)) break;
        }
        #pragma unroll
        for (int i = 0; i < 8; i++)
          #pragma unroll
          for (int g = 0; g < 4; g++)
            acc[g] = MFMA(__builtin_bit_cast(bf16x8, Af[i]),
                          __builtin_bit_cast(bf16x8, wh0[g][i]), acc[g], 0, 0, 0);
      }
      // h1(t-1): check early-issued data, retry on sentinel
      G_WAIT4(Bf);
      for (;;){
        int ok = 1;
        #pragma unroll
        for (int i = 0; i < 4; i++) ok &= frag_ok(Bf[i]);
        if (__all(ok)) break;
        G_LOAD4W(Bf, Ah);
      }
      #pragma unroll
      for (int i = 0; i < 4; i++)
        #pragma unroll
        for (int g = 0; g < 4; g++){
          f32x4 bw = (i == 0) ? wh1[g] : wlds[(g*24 + wv*3 + (i-1))*64 + l];
          acc[g] = MFMA(__builtin_bit_cast(bf16x8, Bf[i]),
                        __builtin_bit_cast(bf16x8, bw), acc[g], 0, 0, 0);
        }
      {
        int r0 = (l >> 4)*4, cj = l & 15;
        #pragma unroll
        for (int g = 0; g < 4; g++)
          #pragma unroll
          for (int i2 = 0; i2 < 4; i2++)
            gl[wv*1024 + g*256 + (r0+i2)*16 + cj] = acc[g][i2];
      }
      __syncthreads();                          // B: partials in gl
      if (tid < 256){
        float s0=0.f, s1=0.f, s2=0.f, s3=0.f;
        #pragma unroll
        for (int wq = 0; wq < 8; wq++){
          s0 += gl[wq*1024 + tid];
          s1 += gl[wq*1024 + 256 + tid];
          s2 += gl[wq*1024 + 512 + tid];
          s3 += gl[wq*1024 + 768 + tid];
        }
        float c2 = sigm(s1)*creg + sigm(s0)*tanh_(s2);
        float h2 = sigm(s3)*tanh_(c2);
        creg = c2;
        out[((long)b_*TT + t)*2048 + cell*1024 + jb*16 + j] = h2;
        u32 lo = f2b(h2), hi = __shfl_down(lo, 1);
        if (!(tid & 1)){
          long idx = ((((long)(t & 3)*2 + cell)*16 + b_)*1024 + jb*16 + j) >> 1;
          g_store32(h1d + idx, lo | (hi << 16));   // fire-and-forget
        }
      }
      __syncthreads();                          // C: gl safe to reuse
    }
  }
}

extern "C" void kernel_launch(void* const* d_in, const int* in_sizes, int n_in,
                              void* d_out, int out_size, void* d_ws, size_t ws_size,
                              hipStream_t stream){
  const int*   inputs = (const int*)d_in[0];
  const float* emb    = (const float*)d_in[1];
  const float* wih0   = (const float*)d_in[2];
  const float* whh0   = (const float*)d_in[3];
  const float* bih0   = (const float*)d_in[4];
  const float* bhh0   = (const float*)d_in[5];
  const float* wih1   = (const float*)d_in[6];
  const float* whh1   = (const float*)d_in[7];
  const float* bih1   = (const float*)d_in[8];
  const float* bhh1   = (const float*)d_in[9];
  float* out = (float*)d_out;
  char* ws = (char*)d_ws;

  float* b0    = (float*)(ws + OFS_B0);
  float* b1    = (float*)(ws + OFS_B1);
  u16*   Xb    = (u16*)(ws + OFS_X);
  u16*   Wih0p = (u16*)(ws + OFS_WIH0);
  u16*   Whh0p = (u16*)(ws + OFS_WHH0);
  u16*   W1p   = (u16*)(ws + OFS_W1);
  u16*   h0a   = (u16*)(ws + OFS_H0);
  u16*   h1r   = (u16*)(ws + OFS_H1);
  unsigned long long* h1z = (unsigned long long*)(ws + OFS_H1 + 196608ul);

  // arm sentinels: full h0 history + h1 ring slots 0-2 (slot 3 zeroed by k_bias)
  hipMemsetAsync(ws + OFS_H0, 0xFF, 33554432ul, stream);
  hipMemsetAsync(ws + OFS_H1, 0xFF, 196608ul, stream);
  k_bias <<<32,   256, 0, stream>>>(bih0, bhh0, bih1, bhh1, b0, b1, h1z);
  k_embed<<<8192, 256, 0, stream>>>(inputs, emb, Xb);
  k_pack <<<4096, 256, 0, stream>>>(wih0, (const float*)0, 1024, 0, Wih0p);
  k_pack <<<4096, 256, 0, stream>>>(whh0, (const float*)0, 1024, 0, Whh0p);
  k_pack <<<12288,256, 0, stream>>>(wih1, whh1, 2048, 1024, W1p);

  const int smem_bytes = 32768 + 98304;   // gl 32KB + l1 h1-weight frags 96KB
  hipFuncSetAttribute(reinterpret_cast<const void*>(&k_fused),
                      hipFuncAttributeMaxDynamicSharedMemorySize, smem_bytes);
  k_fused<<<256, 512, smem_bytes, stream>>>(Wih0p, Whh0p, W1p, b0, b1, Xb,
                                            h0a, h1r, out);
}